// Round 20
// baseline (61.101 us; speedup 1.0000x reference)
//
#include <hip/hip_runtime.h>

typedef unsigned short u16;
typedef unsigned int u32;
typedef __bf16 bf16x8 __attribute__((ext_vector_type(8)));
typedef float f32x4 __attribute__((ext_vector_type(4)));

#define GLD_LDS(gptr, lptr) \
  __builtin_amdgcn_global_load_lds((const __attribute__((address_space(1))) void*)(gptr), \
                                   (__attribute__((address_space(3))) void*)(lptr), 16, 0, 0)

__device__ __forceinline__ u16 f2b(float f) {
  union { __bf16 h; u16 u; } v; v.h = (__bf16)f; return v.u;
}
__device__ __forceinline__ float elu1(float v) {
  return v > 0.f ? v : (__expf(v) - 1.f);
}

// ---------------- 64x64 transpose-convert tile (f32 [R][C] -> bf16 [C][R]) ----------------
__device__ void transpose_tile(float (*tbuf)[65], const float* __restrict__ src,
                               u16* __restrict__ dst, int R, int C, int tr, int tc,
                               size_t zoff) {
  const int tid = threadIdx.x;
  const float* sp = src + zoff + (size_t)(tr * 64) * C + tc * 64;
#pragma unroll
  for (int i = 0; i < 4; i++) {
    const int rr = (tid >> 4) + i * 16, f = tid & 15;
    float4 v = *reinterpret_cast<const float4*>(sp + (size_t)rr * C + f * 4);
    tbuf[rr][f * 4 + 0] = v.x; tbuf[rr][f * 4 + 1] = v.y;
    tbuf[rr][f * 4 + 2] = v.z; tbuf[rr][f * 4 + 3] = v.w;
  }
  __syncthreads();
  u16* dp = dst + zoff + (size_t)(tc * 64) * R + tr * 64;
#pragma unroll
  for (int i = 0; i < 4; i++) {
    const int u = tid + i * 256;
    const int c = u >> 4, rq = u & 15;
    ushort4 w;
    w.x = f2b(tbuf[rq * 4 + 0][c]); w.y = f2b(tbuf[rq * 4 + 1][c]);
    w.z = f2b(tbuf[rq * 4 + 2][c]); w.w = f2b(tbuf[rq * 4 + 3][c]);
    *reinterpret_cast<ushort4*>(dp + (size_t)c * R + rq * 4) = w;
  }
}

// ---------------- routing, stage 1: per-chunk histogram ----------------
__device__ void hist_body(int rb, const int* __restrict__ cat, int* __restrict__ cnts) {
  __shared__ int c8[8];
  const int tid = threadIdx.x;
  if (tid < 8) c8[tid] = 0;
  __syncthreads();
  if (tid < 128) atomicAdd(&c8[cat[rb * 128 + tid]], 1);
  __syncthreads();
  if (tid < 8) cnts[rb * 8 + tid] = c8[tid];
}

// ---------------- routing, stage 2: independent prefix + scatter ----------------
__device__ void scatter_body(int rb, const int* __restrict__ cat,
                             const int* __restrict__ cnts,
                             int* __restrict__ list, int* __restrict__ off) {
  __shared__ int lc[512];
  __shared__ int lcur[8];
  __shared__ int starts[8];
  const int tid = threadIdx.x;
  lc[tid] = cnts[tid];
  lc[tid + 256] = cnts[tid + 256];
  if (tid < 8) lcur[tid] = 0;
  __syncthreads();
  if (tid < 8) {
    const int c = tid;
    int base = 0;
    for (int cc = 0; cc < c; cc++) {
      int s = 0;
      for (int b = 0; b < 64; b++) s += lc[b * 8 + cc];
      base += s;
    }
    int pre = 0;
    for (int b = 0; b < rb; b++) pre += lc[b * 8 + c];
    starts[c] = base + pre;
    if (rb == 0) {
      off[c] = base;
      if (c == 7) {
        int s = 0;
        for (int b = 0; b < 64; b++) s += lc[b * 8 + 7];
        off[8] = base + s;
      }
    }
  }
  __syncthreads();
  if (tid < 128) {
    const int idx = rb * 128 + tid;
    const int c = cat[idx];
    const int r = atomicAdd(&lcur[c], 1);
    list[starts[c] + r] = idx;
  }
}

// ---------------- front kernel: W_in transpose + histogram ----------------
__global__ __launch_bounds__(256) void wsmall(const float* __restrict__ W_in,
                                              const int* __restrict__ cat,
                                              u16* __restrict__ o0, int* __restrict__ cnts) {
  __shared__ float tbuf[64][65];
  const int bid = blockIdx.x;
  if (bid >= 128) { hist_body(bid - 128, cat, cnts); return; }
  transpose_tile(tbuf, W_in, o0, 512, 1024, bid >> 4, bid & 15, 0);
}

// ---------------- unified GEMM + T1 swizzle ----------------
// L1: BM=128, BN=128 (m97 shape), 4 waves each owning 64x64 (acc[4][4]);
//     A = x f32 reg-staged (2 rows/thread); grid (128,14):
//     y<4 GEMM(512), y==4 scatter, y==5..12 W1-T, y==13 W2-T(x<64)/bias-init(x>=64).
// L2: BM=64, BN=128 (R13/R16-proven), gathered rows, fused L3 PV + atomicAdd. 544 blocks.

template<int LAYER, int BN, int K, int N>
__global__ __launch_bounds__(256, (LAYER == 1) ? 3 : 4) void gemm_t(
    const float* __restrict__ Xf, const u16* __restrict__ A,
    const u16* __restrict__ Bw, const float* __restrict__ bias,
    const int* __restrict__ list, const int* __restrict__ off,
    u16* __restrict__ outb, float* __restrict__ outf,
    const int* __restrict__ cat, const int* __restrict__ cnts,
    int* __restrict__ wlist, int* __restrict__ woff,
    const float* __restrict__ Wc1, const float* __restrict__ Wc2,
    u16* __restrict__ o1, u16* __restrict__ o2,
    const float* __restrict__ b2r) {
  constexpr int BM = (LAYER == 1) ? 128 : 64;
  constexpr int MR = BM / 32;                     // A-frag repeats per wave (4 or 2)
  constexpr int NR = BN / 32;                     // B-frag repeats per wave (4)
  struct GBuf { alignas(16) u16 As[2][BM * 32]; alignas(16) u16 Bs[2][BN * 32]; };
  __shared__ union SM {
    GBuf g;
    float tbuf[64][65];
    u16 ht[64 * 136];                             // L2 epilogue h tile
  } sm;

  const int tid = threadIdx.x;

  if constexpr (LAYER == 1) {
    if (blockIdx.y >= 4) {
      if (blockIdx.y == 4) {                      // routing scatter
        if (blockIdx.x < 64) scatter_body(blockIdx.x, cat, cnts, wlist, woff);
      } else if (blockIdx.y <= 12) {              // W1 [8][1024][512] -> [8][512][1024]
        const int t = (blockIdx.y - 5) * 128 + blockIdx.x;
        const int z = t >> 7, rem = t & 127;
        transpose_tile(sm.tbuf, Wc1, o1, 1024, 512, rem >> 3, rem & 7,
                       (size_t)z * 1024 * 512);
      } else if (blockIdx.x < 64) {               // W2 [8][512][64] -> [8][64][512]
        const int t = blockIdx.x, z = t >> 3;
        transpose_tile(sm.tbuf, Wc2, o2, 512, 64, t & 7, 0, (size_t)z * 512 * 64);
      } else {                                    // bias-init: 128 rows/block
        const int r = (blockIdx.x - 64) * 128 + (tid >> 1);
        const int co = (tid & 1) * 32;
        const int c = cat[r];
#pragma unroll
        for (int q = 0; q < 8; q++) {
          float4 v = *reinterpret_cast<const float4*>(b2r + c * 64 + co + q * 4);
          *reinterpret_cast<float4*>(outf + (size_t)r * 64 + co + q * 4) = v;
        }
      }
      return;
    }
  }

  // ---- T1: XCD-chunked bijective block swizzle ----
  int tidx, col0;
  if constexpr (LAYER == 1) {
    const int orig = blockIdx.y * 128 + blockIdx.x;    // 0..511
    const int work = (orig & 7) * 64 + (orig >> 3);    // bijective over 512
    tidx = work >> 3;                                  // row tile 0..63
    col0 = (work & 7) * BN;
  } else {
    const int orig = blockIdx.y * 136 + blockIdx.x;    // 0..543
    const int work = (orig & 7) * 68 + (orig >> 3);    // bijective over 544
    tidx = work >> 2;                                  // grouped row tile 0..135
    col0 = (work & 3) * BN;
  }

  const int wave = tid >> 6, lane = tid & 63;

  int e = 0, start = 0, cnt = 0, rowbase;
  if constexpr (LAYER == 1) {
    rowbase = tidx * BM;
  } else {
    int t = tidx;
    int found = -1;
    for (e = 0; e < 8; e++) {
      int tiles = (off[e + 1] - off[e] + 63) >> 6;
      if (t < tiles) { found = e; break; }
      t -= tiles;
    }
    if (found < 0) return;
    start = off[e];
    cnt = off[e + 1] - start;
    rowbase = t * 64;
  }

  const int srow = tid >> 2, skc = tid & 3;
  const int kxs = (skc ^ (srow & 3)) * 8;

  const float* ax0 = nullptr;
  const float* ax1 = nullptr;
  const u16* a_src = nullptr;
  if constexpr (LAYER == 1) {
    ax0 = Xf + (size_t)(rowbase + srow) * K + kxs;
    ax1 = ax0 + (size_t)64 * K;
  } else {
    int gr = list[start + min(rowbase + srow, cnt - 1)];
    a_src = A + (size_t)gr * K + kxs;
  }
  const u16* Bbase = Bw + (LAYER == 1 ? (size_t)0 : (size_t)e * N * K);
  const u16* b_src0 = Bbase + (size_t)(col0 + srow) * K + kxs;
  const u16* b_src1 = Bbase + (size_t)(col0 + 64 + srow) * K + kxs;

  const int wbase = wave * 512;

  const int wy = wave & 1, wx = wave >> 1;
  const int fr = lane & 15, kg = lane >> 4;
  const int kx = (kg ^ (fr & 3)) * 8;
  const int ar0 = (wy * (BM / 2) + fr) * 32 + kx;
  const int br0 = (wx * (BN / 2) + fr) * 32 + kx;

  f32x4 acc[MR][NR] = {};

  float4 va0, va1, va2, va3;                      // L1 A in-flight (2 rows x 2 float4)
  auto LOAD_A1 = [&](int t) {
    va0 = *reinterpret_cast<const float4*>(ax0 + t * 32);
    va1 = *reinterpret_cast<const float4*>(ax0 + t * 32 + 4);
    va2 = *reinterpret_cast<const float4*>(ax1 + t * 32);
    va3 = *reinterpret_cast<const float4*>(ax1 + t * 32 + 4);
  };
  auto WRITE_A1 = [&](int buf) {
    uint4 w;
    w.x = (u32)f2b(va0.x) | ((u32)f2b(va0.y) << 16);
    w.y = (u32)f2b(va0.z) | ((u32)f2b(va0.w) << 16);
    w.z = (u32)f2b(va1.x) | ((u32)f2b(va1.y) << 16);
    w.w = (u32)f2b(va1.z) | ((u32)f2b(va1.w) << 16);
    *reinterpret_cast<uint4*>(&sm.g.As[buf][srow * 32 + skc * 8]) = w;
    uint4 u;
    u.x = (u32)f2b(va2.x) | ((u32)f2b(va2.y) << 16);
    u.y = (u32)f2b(va2.z) | ((u32)f2b(va2.w) << 16);
    u.z = (u32)f2b(va3.x) | ((u32)f2b(va3.y) << 16);
    u.w = (u32)f2b(va3.z) | ((u32)f2b(va3.w) << 16);
    *reinterpret_cast<uint4*>(&sm.g.As[buf][(64 + srow) * 32 + skc * 8]) = u;
  };
  auto COMPUTE = [&](int buf) {
    bf16x8 af[MR], bfv[NR];
#pragma unroll
    for (int m = 0; m < MR; m++) af[m] = *(const bf16x8*)&sm.g.As[buf][ar0 + m * 16 * 32];
#pragma unroll
    for (int n = 0; n < NR; n++) bfv[n] = *(const bf16x8*)&sm.g.Bs[buf][br0 + n * 16 * 32];
#pragma unroll
    for (int m = 0; m < MR; m++)
#pragma unroll
      for (int n = 0; n < NR; n++)
        acc[m][n] = __builtin_amdgcn_mfma_f32_16x16x32_bf16(af[m], bfv[n], acc[m][n], 0, 0, 0);
  };

  constexpr int NK = K / 32;
  if constexpr (LAYER == 1) LOAD_A1(0);
  else GLD_LDS(a_src, &sm.g.As[0][wbase]);
  GLD_LDS(b_src0, &sm.g.Bs[0][wbase]);
  GLD_LDS(b_src1, &sm.g.Bs[0][2048 + wbase]);
  if constexpr (LAYER == 1) WRITE_A1(0);
  __syncthreads();

  for (int it = 0; it < NK; ++it) {
    const int cur = it & 1;
    const int nxt = cur ^ 1;
    if (it + 1 < NK) {
      const int kt = (it + 1) * 32;
      if constexpr (LAYER == 1) LOAD_A1(it + 1);
      else GLD_LDS(a_src + kt, &sm.g.As[nxt][wbase]);
      GLD_LDS(b_src0 + kt, &sm.g.Bs[nxt][wbase]);
      GLD_LDS(b_src1 + kt, &sm.g.Bs[nxt][2048 + wbase]);
    }
    COMPUTE(cur);
    if constexpr (LAYER == 1) { if (it + 1 < NK) WRITE_A1(nxt); }
    __syncthreads();
  }

  if constexpr (LAYER == 1) {
#pragma unroll
    for (int n = 0; n < NR; n++) {
      const int col = col0 + wx * (BN / 2) + n * 16 + fr;
      const float bc = bias[col];
#pragma unroll
      for (int m = 0; m < MR; m++) {
        const int rloc = wy * (BM / 2) + m * 16 + kg * 4;
#pragma unroll
        for (int j = 0; j < 4; j++)
          outb[(size_t)(rowbase + rloc + j) * N + col] = f2b(elu1(acc[m][n][j] + bc));
      }
    }
  } else {
    // ---- fused L3: h(elu) -> LDS [64][136], PV vs W2 k-slice (128), atomicAdd into out ----
#pragma unroll
    for (int n = 0; n < NR; n++) {
      const int lcol = wx * 64 + n * 16 + fr;          // 0..127
      const float bc = bias[e * N + col0 + lcol];
#pragma unroll
      for (int m = 0; m < MR; m++) {
        const int rl = wy * 32 + m * 16 + kg * 4;
#pragma unroll
        for (int j = 0; j < 4; j++)
          sm.ht[(rl + j) * 136 + lcol] = f2b(elu1(acc[m][n][j] + bc));
      }
    }
    __syncthreads();

    const u16* w2p = o2 + (size_t)e * 64 * 512 + col0;  // W2[e][ocol][k] k-slice
    f32x4 po[2][2] = {};
#pragma unroll
    for (int ks = 0; ks < 4; ks++) {
      bf16x8 pa[2], pb[2];
#pragma unroll
      for (int m = 0; m < 2; m++)
        pa[m] = *(const bf16x8*)&sm.ht[(wy * 32 + m * 16 + fr) * 136 + ks * 32 + kg * 8];
#pragma unroll
      for (int n = 0; n < 2; n++)
        pb[n] = *(const bf16x8*)&w2p[(size_t)(wx * 32 + n * 16 + fr) * 512 + ks * 32 + kg * 8];
#pragma unroll
      for (int m = 0; m < 2; m++)
#pragma unroll
        for (int n = 0; n < 2; n++)
          po[m][n] = __builtin_amdgcn_mfma_f32_16x16x32_bf16(pa[m], pb[n], po[m][n], 0, 0, 0);
    }
#pragma unroll
    for (int n = 0; n < 2; n++) {
      const int oc = wx * 32 + n * 16 + fr;
#pragma unroll
      for (int m = 0; m < 2; m++) {
        const int sl0 = rowbase + wy * 32 + m * 16 + kg * 4;
#pragma unroll
        for (int j = 0; j < 4; j++) {
          const int slot = sl0 + j;
          if (slot < cnt)
            atomicAdd(&outf[(size_t)list[start + slot] * 64 + oc], po[m][n][j]);
        }
      }
    }
  }
}

// ---------------- launch ----------------

extern "C" void kernel_launch(void* const* d_in, const int* in_sizes, int n_in,
                              void* d_out, int out_size, void* d_ws, size_t ws_size,
                              hipStream_t stream) {
  const float* x    = (const float*)d_in[0];
  const int*   cat  = (const int*)d_in[1];
  const float* W_in = (const float*)d_in[2];
  const float* b_in = (const float*)d_in[3];
  const float* W1   = (const float*)d_in[4];
  const float* b1   = (const float*)d_in[5];
  const float* W2   = (const float*)d_in[6];
  const float* b2   = (const float*)d_in[7];
  float* out = (float*)d_out;

  char* p = (char*)d_ws;
  u16* midb = (u16*)p; p += (size_t)8192 * 1024 * 2;   // 16 MB
  u16* wtin = (u16*)p; p += (size_t)1024 * 512 * 2;    // 1 MB
  u16* w1t  = (u16*)p; p += (size_t)8 * 512 * 1024 * 2;// 8 MB
  u16* w2t  = (u16*)p; p += (size_t)8 * 64 * 512 * 2;  // 0.5 MB
  int* list = (int*)p; p += (size_t)8192 * 4;          // 32 KB
  int* off  = (int*)p; p += 64;
  int* cnts = (int*)p; p += 64 * 8 * 4;

  // D1: W_in transpose + histogram
  wsmall<<<192, 256, 0, stream>>>(W_in, cat, wtin, cnts);

  // D2: L1 gemm 128x128 (y<4) + riders (scatter y==4, W1-T y==5..12,
  //     W2-T/bias-init y==13)
  gemm_t<1, 128, 512, 1024><<<dim3(128, 14), 256, 0, stream>>>(
      x, nullptr, wtin, b_in, nullptr, nullptr, midb, out,
      cat, cnts, list, off, W1, W2, w1t, w2t, b2);

  // D3: fused L2+L3, BN=128, 544 blocks (R13/R16-measured best config)
  gemm_t<2, 128, 1024, 512><<<dim3(136, 4), 256, 0, stream>>>(
      nullptr, midb, w1t, b1, list, off, nullptr, out,
      nullptr, nullptr, nullptr, nullptr, nullptr, nullptr, nullptr, w2t, nullptr);
}

// Round 21
// 59.591 us; speedup vs baseline: 1.0253x; 1.0253x over previous
//
#include <hip/hip_runtime.h>

typedef unsigned short u16;
typedef unsigned int u32;
typedef __bf16 bf16x8 __attribute__((ext_vector_type(8)));
typedef float f32x4 __attribute__((ext_vector_type(4)));

#define GLD_LDS(gptr, lptr) \
  __builtin_amdgcn_global_load_lds((const __attribute__((address_space(1))) void*)(gptr), \
                                   (__attribute__((address_space(3))) void*)(lptr), 16, 0, 0)

__device__ __forceinline__ u16 f2b(float f) {
  union { __bf16 h; u16 u; } v; v.h = (__bf16)f; return v.u;
}
__device__ __forceinline__ float elu1(float v) {
  return v > 0.f ? v : (__expf(v) - 1.f);
}

// ---------------- 64x64 transpose-convert tile (f32 [R][C] -> bf16 [C][R]) ----------------
__device__ void transpose_tile(float (*tbuf)[65], const float* __restrict__ src,
                               u16* __restrict__ dst, int R, int C, int tr, int tc,
                               size_t zoff) {
  const int tid = threadIdx.x;
  const float* sp = src + zoff + (size_t)(tr * 64) * C + tc * 64;
#pragma unroll
  for (int i = 0; i < 4; i++) {
    const int rr = (tid >> 4) + i * 16, f = tid & 15;
    float4 v = *reinterpret_cast<const float4*>(sp + (size_t)rr * C + f * 4);
    tbuf[rr][f * 4 + 0] = v.x; tbuf[rr][f * 4 + 1] = v.y;
    tbuf[rr][f * 4 + 2] = v.z; tbuf[rr][f * 4 + 3] = v.w;
  }
  __syncthreads();
  u16* dp = dst + zoff + (size_t)(tc * 64) * R + tr * 64;
#pragma unroll
  for (int i = 0; i < 4; i++) {
    const int u = tid + i * 256;
    const int c = u >> 4, rq = u & 15;
    ushort4 w;
    w.x = f2b(tbuf[rq * 4 + 0][c]); w.y = f2b(tbuf[rq * 4 + 1][c]);
    w.z = f2b(tbuf[rq * 4 + 2][c]); w.w = f2b(tbuf[rq * 4 + 3][c]);
    *reinterpret_cast<ushort4*>(dp + (size_t)c * R + rq * 4) = w;
  }
}

// ---------------- routing, stage 1: per-chunk histogram ----------------
__device__ void hist_body(int rb, const int* __restrict__ cat, int* __restrict__ cnts) {
  __shared__ int c8[8];
  const int tid = threadIdx.x;
  if (tid < 8) c8[tid] = 0;
  __syncthreads();
  if (tid < 128) atomicAdd(&c8[cat[rb * 128 + tid]], 1);
  __syncthreads();
  if (tid < 8) cnts[rb * 8 + tid] = c8[tid];
}

// ---------------- routing, stage 2: independent prefix + scatter ----------------
__device__ void scatter_body(int rb, const int* __restrict__ cat,
                             const int* __restrict__ cnts,
                             int* __restrict__ list, int* __restrict__ off) {
  __shared__ int lc[512];
  __shared__ int lcur[8];
  __shared__ int starts[8];
  const int tid = threadIdx.x;
  lc[tid] = cnts[tid];
  lc[tid + 256] = cnts[tid + 256];
  if (tid < 8) lcur[tid] = 0;
  __syncthreads();
  if (tid < 8) {
    const int c = tid;
    int base = 0;
    for (int cc = 0; cc < c; cc++) {
      int s = 0;
      for (int b = 0; b < 64; b++) s += lc[b * 8 + cc];
      base += s;
    }
    int pre = 0;
    for (int b = 0; b < rb; b++) pre += lc[b * 8 + c];
    starts[c] = base + pre;
    if (rb == 0) {
      off[c] = base;
      if (c == 7) {
        int s = 0;
        for (int b = 0; b < 64; b++) s += lc[b * 8 + 7];
        off[8] = base + s;
      }
    }
  }
  __syncthreads();
  if (tid < 128) {
    const int idx = rb * 128 + tid;
    const int c = cat[idx];
    const int r = atomicAdd(&lcur[c], 1);
    list[starts[c] + r] = idx;
  }
}

// ---------------- front kernel: W_in transpose + histogram ----------------
__global__ __launch_bounds__(256) void wsmall(const float* __restrict__ W_in,
                                              const int* __restrict__ cat,
                                              u16* __restrict__ o0, int* __restrict__ cnts) {
  __shared__ float tbuf[64][65];
  const int bid = blockIdx.x;
  if (bid >= 128) { hist_body(bid - 128, cat, cnts); return; }
  transpose_tile(tbuf, W_in, o0, 512, 1024, bid >> 4, bid & 15, 0);
}

// ---------------- unified GEMM + T1 swizzle (R3 loop) ----------------
// L1 (BN=128): A = x f32 reg-staged; riders y==8 scatter, y==9..16 W1-T, y==17 W2-T,
//              y==18 out bias-init (writes outf = out).
// L2 (BN=128): gathered rows, fused L3 PV epilogue + atomicAdd into out. 544 blocks.

template<int LAYER, int BN, int K, int N>
__global__ __launch_bounds__(256, 4) void gemm_t(
    const float* __restrict__ Xf, const u16* __restrict__ A,
    const u16* __restrict__ Bw, const float* __restrict__ bias,
    const int* __restrict__ list, const int* __restrict__ off,
    u16* __restrict__ outb, float* __restrict__ outf,
    const int* __restrict__ cat, const int* __restrict__ cnts,
    int* __restrict__ wlist, int* __restrict__ woff,
    const float* __restrict__ Wc1, const float* __restrict__ Wc2,
    u16* __restrict__ o1, u16* __restrict__ o2,
    const float* __restrict__ b2r) {
  struct GBuf { alignas(16) u16 As[2][2048]; alignas(16) u16 Bs[2][BN * 32]; };
  __shared__ union SM {
    GBuf g;
    float tbuf[64][65];
    u16 ht[64 * 136];                      // L2 epilogue h tile [64][136] (pad)
  } sm;

  const int tid = threadIdx.x;

  if constexpr (LAYER == 1) {
    if (blockIdx.y == 8) {
      if (blockIdx.x < 64) scatter_body(blockIdx.x, cat, cnts, wlist, woff);
      return;
    }
    if (blockIdx.y >= 9) {
      if (blockIdx.y <= 16) {
        const int t = (blockIdx.y - 9) * 128 + blockIdx.x;
        const int z = t >> 7, rem = t & 127;
        transpose_tile(sm.tbuf, Wc1, o1, 1024, 512, rem >> 3, rem & 7,
                       (size_t)z * 1024 * 512);
      } else if (blockIdx.y == 17) {
        if (blockIdx.x < 64) {
          const int t = blockIdx.x, z = t >> 3;
          transpose_tile(sm.tbuf, Wc2, o2, 512, 64, t & 7, 0, (size_t)z * 512 * 64);
        }
      } else {                             // y==18: out[r] = b2[cat[r]]  (64 rows/block)
        const int r = blockIdx.x * 64 + (tid >> 2);
        const int co = (tid & 3) * 16;
        const int c = cat[r];
#pragma unroll
        for (int q = 0; q < 4; q++) {
          float4 v = *reinterpret_cast<const float4*>(b2r + c * 64 + co + q * 4);
          *reinterpret_cast<float4*>(outf + (size_t)r * 64 + co + q * 4) = v;
        }
      }
      return;
    }
  }

  // ---- T1: XCD-chunked bijective block swizzle ----
  int tidx, col0;
  if constexpr (LAYER == 1) {
    const int orig = blockIdx.y * 128 + blockIdx.x;
    const int work = (orig & 7) * 128 + (orig >> 3);
    tidx = work >> 3;
    col0 = (work & 7) * BN;
  } else {
    const int orig = blockIdx.y * 136 + blockIdx.x;    // 0..543
    const int work = (orig & 7) * 68 + (orig >> 3);    // bijective over 544
    tidx = work >> 2;                                  // grouped row tile 0..135
    col0 = (work & 3) * BN;
  }

  const int wave = tid >> 6, lane = tid & 63;

  int e = 0, start = 0, cnt = 0, rowbase;
  if constexpr (LAYER == 1) {
    rowbase = tidx * 64;
  } else {
    int t = tidx;
    int found = -1;
    for (e = 0; e < 8; e++) {
      int tiles = (off[e + 1] - off[e] + 63) >> 6;
      if (t < tiles) { found = e; break; }
      t -= tiles;
    }
    if (found < 0) return;
    start = off[e];
    cnt = off[e + 1] - start;
    rowbase = t * 64;
  }

  const int srow = tid >> 2, skc = tid & 3;
  const int kxs = (skc ^ (srow & 3)) * 8;

  const float* ax = nullptr;
  const u16* a_src = nullptr;
  if constexpr (LAYER == 1) {
    ax = Xf + (size_t)(rowbase + srow) * K + kxs;
  } else {
    int gr = list[start + min(rowbase + srow, cnt - 1)];
    a_src = A + (size_t)gr * K + kxs;
  }
  const u16* Bbase = Bw + (LAYER == 1 ? (size_t)0 : (size_t)e * N * K);
  const u16* b_src0 = Bbase + (size_t)(col0 + srow) * K + kxs;
  const u16* b_src1 = Bbase + (size_t)(col0 + 64 + srow) * K + kxs;

  const int wbase = wave * 512;

  constexpr int NR = BN / 32;
  const int wy = wave & 1, wx = wave >> 1;
  const int fr = lane & 15, kg = lane >> 4;
  const int kx = (kg ^ (fr & 3)) * 8;
  const int ar0 = (wy * 32 + fr) * 32 + kx;
  const int br0 = (wx * (BN / 2) + fr) * 32 + kx;

  f32x4 acc[2][NR] = {};

  float4 va0, va1;
  auto LOAD_A1 = [&](int t) {
    va0 = *reinterpret_cast<const float4*>(ax + t * 32);
    va1 = *reinterpret_cast<const float4*>(ax + t * 32 + 4);
  };
  auto WRITE_A1 = [&](int buf) {
    uint4 w;
    w.x = (u32)f2b(va0.x) | ((u32)f2b(va0.y) << 16);
    w.y = (u32)f2b(va0.z) | ((u32)f2b(va0.w) << 16);
    w.z = (u32)f2b(va1.x) | ((u32)f2b(va1.y) << 16);
    w.w = (u32)f2b(va1.z) | ((u32)f2b(va1.w) << 16);
    *reinterpret_cast<uint4*>(&sm.g.As[buf][srow * 32 + skc * 8]) = w;
  };
  auto COMPUTE = [&](int buf) {
    bf16x8 af[2], bfv[NR];
#pragma unroll
    for (int m = 0; m < 2; m++) af[m] = *(const bf16x8*)&sm.g.As[buf][ar0 + m * 16 * 32];
#pragma unroll
    for (int n = 0; n < NR; n++) bfv[n] = *(const bf16x8*)&sm.g.Bs[buf][br0 + n * 16 * 32];
#pragma unroll
    for (int m = 0; m < 2; m++)
#pragma unroll
      for (int n = 0; n < NR; n++)
        acc[m][n] = __builtin_amdgcn_mfma_f32_16x16x32_bf16(af[m], bfv[n], acc[m][n], 0, 0, 0);
  };

  constexpr int NK = K / 32;
  if constexpr (LAYER == 1) LOAD_A1(0);
  else GLD_LDS(a_src, &sm.g.As[0][wbase]);
  GLD_LDS(b_src0, &sm.g.Bs[0][wbase]);
  if constexpr (BN == 128) GLD_LDS(b_src1, &sm.g.Bs[0][2048 + wbase]);
  if constexpr (LAYER == 1) WRITE_A1(0);
  __syncthreads();

  for (int it = 0; it < NK; ++it) {
    const int cur = it & 1;
    const int nxt = cur ^ 1;
    if (it + 1 < NK) {
      const int kt = (it + 1) * 32;
      if constexpr (LAYER == 1) LOAD_A1(it + 1);
      else GLD_LDS(a_src + kt, &sm.g.As[nxt][wbase]);
      GLD_LDS(b_src0 + kt, &sm.g.Bs[nxt][wbase]);
      if constexpr (BN == 128) GLD_LDS(b_src1 + kt, &sm.g.Bs[nxt][2048 + wbase]);
    }
    COMPUTE(cur);
    if constexpr (LAYER == 1) { if (it + 1 < NK) WRITE_A1(nxt); }
    __syncthreads();
  }

  if constexpr (LAYER == 1) {
#pragma unroll
    for (int n = 0; n < NR; n++) {
      const int col = col0 + wx * (BN / 2) + n * 16 + fr;
      const float bc = bias[col];
#pragma unroll
      for (int m = 0; m < 2; m++) {
        const int rloc = wy * 32 + m * 16 + kg * 4;
#pragma unroll
        for (int j = 0; j < 4; j++)
          outb[(size_t)(rowbase + rloc + j) * N + col] = f2b(elu1(acc[m][n][j] + bc));
      }
    }
  } else {
    // ---- fused L3: h(elu) -> LDS [64][136], PV vs W2 k-slice (128), atomicAdd into out ----
#pragma unroll
    for (int n = 0; n < NR; n++) {
      const int lcol = wx * 64 + n * 16 + fr;          // 0..127
      const float bc = bias[e * N + col0 + lcol];
#pragma unroll
      for (int m = 0; m < 2; m++) {
        const int rl = wy * 32 + m * 16 + kg * 4;
#pragma unroll
        for (int j = 0; j < 4; j++)
          sm.ht[(rl + j) * 136 + lcol] = f2b(elu1(acc[m][n][j] + bc));
      }
    }
    __syncthreads();

    const u16* w2p = o2 + (size_t)e * 64 * 512 + col0;  // W2[e][ocol][k] k-slice
    f32x4 po[2][2] = {};
#pragma unroll
    for (int ks = 0; ks < 4; ks++) {
      bf16x8 pa[2], pb[2];
#pragma unroll
      for (int m = 0; m < 2; m++)
        pa[m] = *(const bf16x8*)&sm.ht[(wy * 32 + m * 16 + fr) * 136 + ks * 32 + kg * 8];
#pragma unroll
      for (int n = 0; n < 2; n++)
        pb[n] = *(const bf16x8*)&w2p[(size_t)(wx * 32 + n * 16 + fr) * 512 + ks * 32 + kg * 8];
#pragma unroll
      for (int m = 0; m < 2; m++)
#pragma unroll
        for (int n = 0; n < 2; n++)
          po[m][n] = __builtin_amdgcn_mfma_f32_16x16x32_bf16(pa[m], pb[n], po[m][n], 0, 0, 0);
    }
#pragma unroll
    for (int n = 0; n < 2; n++) {
      const int oc = wx * 32 + n * 16 + fr;
#pragma unroll
      for (int m = 0; m < 2; m++) {
        const int sl0 = rowbase + wy * 32 + m * 16 + kg * 4;
#pragma unroll
        for (int j = 0; j < 4; j++) {
          const int slot = sl0 + j;
          if (slot < cnt)
            atomicAdd(&outf[(size_t)list[start + slot] * 64 + oc], po[m][n][j]);
        }
      }
    }
  }
}

// ---------------- launch ----------------

extern "C" void kernel_launch(void* const* d_in, const int* in_sizes, int n_in,
                              void* d_out, int out_size, void* d_ws, size_t ws_size,
                              hipStream_t stream) {
  const float* x    = (const float*)d_in[0];
  const int*   cat  = (const int*)d_in[1];
  const float* W_in = (const float*)d_in[2];
  const float* b_in = (const float*)d_in[3];
  const float* W1   = (const float*)d_in[4];
  const float* b1   = (const float*)d_in[5];
  const float* W2   = (const float*)d_in[6];
  const float* b2   = (const float*)d_in[7];
  float* out = (float*)d_out;

  char* p = (char*)d_ws;
  u16* midb = (u16*)p; p += (size_t)8192 * 1024 * 2;   // 16 MB
  u16* wtin = (u16*)p; p += (size_t)1024 * 512 * 2;    // 1 MB
  u16* w1t  = (u16*)p; p += (size_t)8 * 512 * 1024 * 2;// 8 MB
  u16* w2t  = (u16*)p; p += (size_t)8 * 64 * 512 * 2;  // 0.5 MB
  int* list = (int*)p; p += (size_t)8192 * 4;          // 32 KB
  int* off  = (int*)p; p += 64;
  int* cnts = (int*)p; p += 64 * 8 * 4;

  // D1: W_in transpose + histogram
  wsmall<<<192, 256, 0, stream>>>(W_in, cat, wtin, cnts);

  // D2: L1 gemm + riders (scatter y==8, W1-T y==9..16, W2-T y==17, bias-init y==18)
  gemm_t<1, 128, 512, 1024><<<dim3(128, 19), 256, 0, stream>>>(
      x, nullptr, wtin, b_in, nullptr, nullptr, midb, out,
      cat, cnts, list, off, W1, W2, w1t, w2t, b2);

  // D3: fused L2+L3, BN=128, 544 blocks (R13/R16-measured best config)
  gemm_t<2, 128, 1024, 512><<<dim3(136, 4), 256, 0, stream>>>(
      nullptr, midb, w1t, b1, list, off, nullptr, out,
      nullptr, nullptr, nullptr, nullptr, nullptr, nullptr, nullptr, w2t, nullptr);
}